// Round 2
// 482.722 us; speedup vs baseline: 1.0452x; 1.0452x over previous
//
#include <hip/hip_runtime.h>
#include <math.h>

// Problem constants (B=16, H=W=128, C=256, PATCH=8)
#define CCH   256      // channels
#define HID   64       // hidden dim of scorer MLP
#define MT    256      // tokens per block in scorer kernel
#define KC    32       // K-chunk staged in LDS
#define XT    258      // padded row stride (dwords) for k-major x tile (8B-aligned rows)
#define NP    256      // patches per image (16x16)
#define NK    179      // kept patches: max(10, int(256*0.7))
#define NSLOT 192      // 12*16 output patch grid slots
#define IMW   128      // image width (tokens)
#define OUTH  96       // output height (12*8)

typedef float f32x4 __attribute__((ext_vector_type(4)));  // native vec for nontemporal

// ---------------- Kernel 1: token scorer (fused 2-layer MLP) ----------------
// grid = totalTokens/MT blocks, 256 threads. Each thread: 8 tokens x 8 hidden.
// v2: register double-buffered staging (global loads for chunk ch+1 issued
//     between barriers, consumed while chunk ch computes) + ds_read_b64
//     vectorized x reads (tokens g*64 + 2*tw + {0,1}).
__global__ __launch_bounds__(256) void scorer_kernel(
    const float* __restrict__ tokens, const float* __restrict__ W1,
    const float* __restrict__ b1, const float* __restrict__ W2,
    const float* __restrict__ b2v, float* __restrict__ tok_imp)
{
    __shared__ float xs[KC * XT];        // x chunk, k-major: xs[k][tok], 33 KB
    __shared__ float ws[KC * HID];       // W1 chunk: ws[k][h], 8 KB
    __shared__ float red[8 * MT];        // layer-2 partial reduction, 8 KB

    const int t  = threadIdx.x;
    const int tw = t & 31;               // token lane (tokens g*64 + 2*tw + {0,1})
    const int hg = t >> 5;               // hidden group (hidden hg*8 .. +7)
    const long base = (long)blockIdx.x * MT;   // global token id base

    float w2r[8];
    float acc[8][8];
    #pragma unroll
    for (int j = 0; j < 8; ++j) w2r[j] = W2[hg * 8 + j];
    {
        float binit[8];
        #pragma unroll
        for (int j = 0; j < 8; ++j) binit[j] = b1[hg * 8 + j];
        #pragma unroll
        for (int i = 0; i < 8; ++i)
            #pragma unroll
            for (int j = 0; j < 8; ++j) acc[i][j] = binit[j];
    }

    const float4* tok4 = (const float4*)(tokens + base * CCH);
    const int f4k = t & 7;       // which float4 of the 32-float k-chunk
    const int tl0 = t >> 3;      // token row 0..31 per pass

    // ---- prefetch chunk 0 into registers ----
    float4 pf[8];
    #pragma unroll
    for (int pass = 0; pass < 8; ++pass)
        pf[pass] = tok4[(long)(tl0 + 32 * pass) * (CCH / 4) + f4k];
    float4 wpf0 = ((const float4*)W1)[t];
    float4 wpf1 = ((const float4*)W1)[t + 256];

    for (int ch = 0; ch < CCH / KC; ++ch) {
        // ---- write staged registers to LDS (transposed to k-major) ----
        #pragma unroll
        for (int pass = 0; pass < 8; ++pass) {
            int tokLocal = tl0 + 32 * pass;
            float4 v = pf[pass];
            int kloc = f4k * 4;
            xs[(kloc + 0) * XT + tokLocal] = v.x;
            xs[(kloc + 1) * XT + tokLocal] = v.y;
            xs[(kloc + 2) * XT + tokLocal] = v.z;
            xs[(kloc + 3) * XT + tokLocal] = v.w;
        }
        ((float4*)ws)[t]       = wpf0;
        ((float4*)ws)[t + 256] = wpf1;
        __syncthreads();

        // ---- issue next chunk's global loads (latency hides under FMAs) ----
        if (ch < CCH / KC - 1) {
            #pragma unroll
            for (int pass = 0; pass < 8; ++pass)
                pf[pass] = tok4[(long)(tl0 + 32 * pass) * (CCH / 4)
                                + (ch + 1) * (KC / 4) + f4k];
            const float4* w14 = (const float4*)(W1 + (ch + 1) * KC * HID);
            wpf0 = w14[t];
            wpf1 = w14[t + 256];
        }

        // ---- FMA inner loop ----
        #pragma unroll
        for (int kk = 0; kk < KC; ++kk) {
            float xv[8], wv[8];
            #pragma unroll
            for (int g = 0; g < 4; ++g) {
                xv[2 * g]     = xs[kk * XT + g * 64 + 2 * tw];      // ds_read_b64
                xv[2 * g + 1] = xs[kk * XT + g * 64 + 2 * tw + 1];
            }
            #pragma unroll
            for (int j = 0; j < 8; ++j) wv[j] = ws[kk * HID + hg * 8 + j];
            #pragma unroll
            for (int i = 0; i < 8; ++i)
                #pragma unroll
                for (int j = 0; j < 8; ++j)
                    acc[i][j] = fmaf(xv[i], wv[j], acc[i][j]);
        }
        __syncthreads();
    }

    // ---- layer 2: relu(h) . W2, partial per hidden-group ----
    #pragma unroll
    for (int i = 0; i < 8; ++i) {
        float p = 0.f;
        #pragma unroll
        for (int j = 0; j < 8; ++j) {
            float h = acc[i][j] > 0.f ? acc[i][j] : 0.f;
            p = fmaf(h, w2r[j], p);
        }
        int g  = i >> 1;
        int lt = g * 64 + 2 * tw + (i & 1);   // this thread's i-th token id
        red[hg * MT + lt] = p;
    }
    __syncthreads();
    float s = b2v[0];
    #pragma unroll
    for (int g = 0; g < 8; ++g) s += red[g * MT + t];
    tok_imp[base + t] = 1.f / (1.f + expf(-s));
}

// ---------------- Kernel 2: per-batch patch scores + stable top-k ----------
// grid = B blocks, 256 threads (one per patch).
// v2: float4 importance loads (same add order), unrolled rank loop,
//     ballot/popcount prefix instead of O(p) serial LDS loop.
__global__ __launch_bounds__(256) void select_kernel(
    const float* __restrict__ tok_imp, int* __restrict__ sel)
{
    __shared__ float s[NP];
    __shared__ unsigned long long wmask[4];
    const int b = blockIdx.x, p = threadIdx.x;
    const int ih = p >> 4, iw = p & 15;
    const float4* tp4 = (const float4*)(tok_imp + (long)b * 16384
                                        + (ih * 8) * IMW + iw * 8);
    float sum = 0.f;
    #pragma unroll
    for (int ti = 0; ti < 8; ++ti) {
        float4 a = tp4[ti * (IMW / 4)];
        float4 c = tp4[ti * (IMW / 4) + 1];
        sum += a.x; sum += a.y; sum += a.z; sum += a.w;   // same order as scalar
        sum += c.x; sum += c.y; sum += c.z; sum += c.w;
    }
    s[p] = sum;                      // mean = sum/64: monotone, rank-identical
    __syncthreads();
    const float sp = s[p];
    int rank = 0;
    #pragma unroll 8
    for (int j = 0; j < NP; ++j) {
        float sj = s[j];
        rank += (sj > sp) || ((sj == sp) && (j < p));   // stable top_k order
    }
    const bool keep = rank < NK;
    const unsigned long long m = __ballot(keep);
    const int wv = p >> 6, ln = p & 63;
    if (ln == 0) wmask[wv] = m;
    __syncthreads();
    if (keep) {
        int pos = __popcll(m & ((1ull << ln) - 1ull));
        #pragma unroll
        for (int w = 0; w < 3; ++w)
            if (w < wv) pos += __popcll(wmask[w]);
        sel[b * NK + pos] = p;       // selected patches in ascending index order
    }
}

// ---------------- Kernel 3: gather kept patches into output grid -----------
// grid = B*NSLOT blocks, 256 threads; each block moves one 64 KB patch.
// v2: nontemporal stores via native ext_vector float4 (output never re-read).
__global__ __launch_bounds__(256) void gather_kernel(
    const float* __restrict__ tokens, const int* __restrict__ sel,
    float* __restrict__ out)
{
    const int bid = blockIdx.x;
    const int b = bid / NSLOT, k = bid % NSLOT;
    const int t = threadIdx.x;
    const int kh = k >> 4, kw = k & 15;
    f32x4* dst4 = (f32x4*)(out + (long)b * OUTH * IMW * CCH);

    if (k >= NK) {
        const f32x4 z = {0.f, 0.f, 0.f, 0.f};
        #pragma unroll
        for (int i = 0; i < 16; ++i) {
            int f = i * 256 + t;                 // f4 index within patch 0..4095
            int ti = f >> 9;                     // 512 f4 per (8-col x 256-ch) row
            int off = f & 511;
            long d = ((long)(kh * 8 + ti) * IMW + kw * 8) * (CCH / 4) + off;
            __builtin_nontemporal_store(z, &dst4[d]);
        }
        return;
    }
    const int p = sel[b * NK + k];
    const int ih = p >> 4, iw = p & 15;
    const f32x4* src4 = (const f32x4*)(tokens + (long)b * 16384 * CCH);
    #pragma unroll
    for (int i = 0; i < 16; ++i) {
        int f = i * 256 + t;
        int ti = f >> 9;
        int off = f & 511;
        long srow = ((long)(ih * 8 + ti) * IMW + iw * 8) * (CCH / 4) + off;
        long drow = ((long)(kh * 8 + ti) * IMW + kw * 8) * (CCH / 4) + off;
        f32x4 v = src4[srow];
        __builtin_nontemporal_store(v, &dst4[drow]);
    }
}

extern "C" void kernel_launch(void* const* d_in, const int* in_sizes, int n_in,
                              void* d_out, int out_size, void* d_ws, size_t ws_size,
                              hipStream_t stream)
{
    const float* tokens = (const float*)d_in[0];
    const float* W1     = (const float*)d_in[1];
    const float* b1     = (const float*)d_in[2];
    const float* W2     = (const float*)d_in[3];
    const float* b2     = (const float*)d_in[4];
    // d_in[5], d_in[6] are H, W scalars (128, 128) — layout hard-coded.

    const int totalTok = in_sizes[0] / CCH;        // B * 16384
    const int B        = totalTok / (IMW * IMW);   // 16

    int*   sel     = (int*)d_ws;                                    // B*NK ints
    float* tok_imp;
    size_t selBytes = (size_t)B * NK * sizeof(int);
    size_t impBytes = (size_t)totalTok * sizeof(float);
    if (ws_size >= selBytes + 256 + impBytes) {
        tok_imp = (float*)((char*)d_ws + ((selBytes + 255) & ~(size_t)255));
    } else {
        // fall back: use head of d_out as scratch (fully overwritten by gather)
        tok_imp = (float*)d_out;
    }

    scorer_kernel<<<totalTok / MT, 256, 0, stream>>>(tokens, W1, b1, W2, b2, tok_imp);
    select_kernel<<<B, 256, 0, stream>>>(tok_imp, sel);
    gather_kernel<<<B * NSLOT, 256, 0, stream>>>(tokens, sel, (float*)d_out);
}